// Round 9
// baseline (222.058 us; speedup 1.0000x reference)
//
#include <hip/hip_runtime.h>
#include <hip/hip_bf16.h>
#include <math.h>

#define NB 512
#define NS 200
#define NH 256
#define TILE_S 32
#define NTILE 7                  // ceil(200/32); last tile ragged (8 real rows, reads clamped)
#define NTASK (NB * NTILE)       // 3584 wave-tasks

// ws float-offset layout
#define OFF_SC 0                                  // scores: 512*200 floats
#define OFF_L  (NB * NS)                          // l: 512*256 floats
#define OFF_UB (OFF_L + NB * NH)                  // Uswz bf16 = 32768 float slots
#define WS_FLOATS_PRE (OFF_UB + (NH * NH) / 2)    // 266240 floats = 1.06 MB

typedef __bf16 bf16x8 __attribute__((ext_vector_type(8)));
typedef float  f32x4  __attribute__((ext_vector_type(4)));

// tanh(x) = 1 - 2/(exp(2x)+1). No clamp needed: e=inf -> 1, e=0 -> -1. ~6 VALU.
__device__ __forceinline__ float tanh_fast(float x) {
  float e = __expf(x + x);
  return fmaf(-2.f, __builtin_amdgcn_rcpf(e + 1.f), 1.f);
}

// ---------------- Kernel 0: precompute l = lastm@W^T (fp32) and swizzled bf16 U ----
// Uswz frag id = ((n_blk*8 + kk)*64 + lane), 8 bf16 each:
// contents U[n_blk*16 + (lane&15)][kk*32 + (lane>>4)*8 + j], j=0..7
__global__ __launch_bounds__(256)
void precompute(const float* __restrict__ lastm, const float* __restrict__ W,
                const float* __restrict__ U,
                float* __restrict__ l_ws, __bf16* __restrict__ Uswz)
{
  const int t = threadIdx.x;
  if (blockIdx.x < NB) {
    const int b = blockIdx.x;
    __shared__ float lm_sm[NH];
    lm_sm[t] = lastm[(size_t)b * NH + t];
    __syncthreads();
    const float4* wrow = (const float4*)(W + (size_t)t * NH);
    const float4* lrow = (const float4*)lm_sm;
    float a0 = 0.f, a1 = 0.f, a2 = 0.f, a3 = 0.f;
#pragma unroll 8
    for (int i = 0; i < NH / 4; ++i) {
      float4 w4 = wrow[i];
      float4 m4 = lrow[i];
      a0 = fmaf(w4.x, m4.x, a0);
      a1 = fmaf(w4.y, m4.y, a1);
      a2 = fmaf(w4.z, m4.z, a2);
      a3 = fmaf(w4.w, m4.w, a3);
    }
    l_ws[(size_t)b * NH + t] = (a0 + a1) + (a2 + a3);
  } else {
    const int id    = (blockIdx.x - NB) * 256 + t;   // 8192 frags
    const int n_blk = id >> 9;
    const int kk    = (id >> 6) & 7;
    const int lane  = id & 63;
    const int row   = n_blk * 16 + (lane & 15);
    const int col   = kk * 32 + (lane >> 4) * 8;
    const float4* s = (const float4*)(U + (size_t)row * NH + col);
    const float4 a = s[0], c = s[1];
    bf16x8 pk;
    pk[0] = (__bf16)a.x; pk[1] = (__bf16)a.y;
    pk[2] = (__bf16)a.z; pk[3] = (__bf16)a.w;
    pk[4] = (__bf16)c.x; pk[5] = (__bf16)c.y;
    pk[6] = (__bf16)c.z; pk[7] = (__bf16)c.w;
    *(bf16x8*)(Uswz + (size_t)id * 8) = pk;
  }
}

// ---------------- Kernel 1: scores, one 32-row tile PER WAVE, barrier-free ----------------
// R6/R8 post-mortem: identical 63 us despite 4x different LDS traffic and 2x
// occupancy -> the block-wide stage->__syncthreads->compute chain was the wall
// (60% of cycles all-waves-stalled). Here each wave is fully independent:
// A (32 rows x 256 k) lives in 64 VGPRs, loaded straight from global; U frags
// stream from L2-resident Uswz; no LDS, no barriers in the PRE path.
template<bool PRE>
__global__ __launch_bounds__(256, 2)
void scores_kernel(const float* __restrict__ mem,    // [B,S,H]
                   const float* __restrict__ lastm,  // [B,H] (fallback)
                   const float* __restrict__ U,      // [H,H] fp32 (fallback)
                   const float* __restrict__ W,      // [H,H] (fallback)
                   const float* __restrict__ V,      // [H]
                   const float* __restrict__ l_ws,   // [B,H] (PRE)
                   const __bf16* __restrict__ Uswz,  // swizzled bf16 U (PRE)
                   float* __restrict__ scores)       // [B,S]
{
  const int wave = threadIdx.x >> 6;
  const int lane = threadIdx.x & 63;
  const int task = blockIdx.x * 4 + wave;     // 0..3583
  const int b    = task / NTILE;
  const int tile = task - b * NTILE;
  const int s0   = tile * TILE_S;
  const int m16  = lane & 15;
  const int quad = lane >> 4;

  // ---- A fragments: rows s0+m16 and s0+16+m16 (clamped), all k. 64 VGPRs ----
  const int r0 = min(s0 + m16, NS - 1);
  const int r1 = min(s0 + 16 + m16, NS - 1);
  const float* rp0 = mem + ((size_t)b * NS + r0) * NH + quad * 8;
  const float* rp1 = mem + ((size_t)b * NS + r1) * NH + quad * 8;

  bf16x8 a_frag[2][8];
#pragma unroll
  for (int kk = 0; kk < 8; ++kk) {
    const float4 lo0 = *(const float4*)(rp0 + kk * 32);
    const float4 hi0 = *(const float4*)(rp0 + kk * 32 + 4);
    const float4 lo1 = *(const float4*)(rp1 + kk * 32);
    const float4 hi1 = *(const float4*)(rp1 + kk * 32 + 4);
    bf16x8 f0, f1;
    f0[0] = (__bf16)lo0.x; f0[1] = (__bf16)lo0.y; f0[2] = (__bf16)lo0.z; f0[3] = (__bf16)lo0.w;
    f0[4] = (__bf16)hi0.x; f0[5] = (__bf16)hi0.y; f0[6] = (__bf16)hi0.z; f0[7] = (__bf16)hi0.w;
    f1[0] = (__bf16)lo1.x; f1[1] = (__bf16)lo1.y; f1[2] = (__bf16)lo1.z; f1[3] = (__bf16)lo1.w;
    f1[4] = (__bf16)hi1.x; f1[5] = (__bf16)hi1.y; f1[6] = (__bf16)hi1.z; f1[7] = (__bf16)hi1.w;
    a_frag[0][kk] = f0;
    a_frag[1][kk] = f1;
  }

  float p[2][4];
#pragma unroll
  for (int mt = 0; mt < 2; ++mt)
#pragma unroll
    for (int reg = 0; reg < 4; ++reg)
      p[mt][reg] = 0.f;

  // ---- n_blk loop: 16 cols at a time; u_frag from L2; no barriers ----
#pragma unroll 1
  for (int n_blk = 0; n_blk < 16; ++n_blk) {
    const int n = n_blk * 16 + m16;

    bf16x8 u_frag[8];
    if (PRE) {
      const __bf16* uw = Uswz + (size_t)n_blk * 4096 + (size_t)lane * 8;
#pragma unroll
      for (int kk = 0; kk < 8; ++kk)
        u_frag[kk] = *(const bf16x8*)(uw + (kk << 9));
    } else {
      const float* urow = U + (size_t)n * NH;
#pragma unroll
      for (int kk = 0; kk < 8; ++kk) {
        const float4 lo = *(const float4*)(urow + kk * 32 + quad * 8);
        const float4 hi = *(const float4*)(urow + kk * 32 + quad * 8 + 4);
        bf16x8 f;
        f[0] = (__bf16)lo.x; f[1] = (__bf16)lo.y;
        f[2] = (__bf16)lo.z; f[3] = (__bf16)lo.w;
        f[4] = (__bf16)hi.x; f[5] = (__bf16)hi.y;
        f[6] = (__bf16)hi.z; f[7] = (__bf16)hi.w;
        u_frag[kk] = f;
      }
    }

    float l_reg, v_reg;
    if (PRE) {
      l_reg = l_ws[(size_t)b * NH + n];
    } else {
      // slow-but-correct fallback: per-lane dot
      const float* lm = lastm + (size_t)b * NH;
      const float* wr = W + (size_t)n * NH;
      float a0 = 0.f;
      for (int i = 0; i < NH; ++i) a0 = fmaf(lm[i], wr[i], a0);
      l_reg = a0;
    }
    v_reg = V[n];

    f32x4 acc0 = {0.f, 0.f, 0.f, 0.f};
    f32x4 acc1 = {0.f, 0.f, 0.f, 0.f};
#pragma unroll
    for (int kk = 0; kk < 8; ++kk) {
      acc0 = __builtin_amdgcn_mfma_f32_16x16x32_bf16(a_frag[0][kk], u_frag[kk], acc0, 0, 0, 0);
      acc1 = __builtin_amdgcn_mfma_f32_16x16x32_bf16(a_frag[1][kk], u_frag[kk], acc1, 0, 0, 0);
    }

    // C/D 16x16: row = quad*4 + reg, col n = m16
#pragma unroll
    for (int reg = 0; reg < 4; ++reg) {
      p[0][reg] = fmaf(tanh_fast(acc0[reg] + l_reg), v_reg, p[0][reg]);
      p[1][reg] = fmaf(tanh_fast(acc1[reg] + l_reg), v_reg, p[1][reg]);
    }
  }

  // ---- reduce over the 16 m16-lanes (n dimension) ----
#pragma unroll
  for (int off = 1; off < 16; off <<= 1) {
#pragma unroll
    for (int mt = 0; mt < 2; ++mt)
#pragma unroll
      for (int reg = 0; reg < 4; ++reg)
        p[mt][reg] += __shfl_xor(p[mt][reg], off);
  }

  if (m16 == 0) {
#pragma unroll
    for (int mt = 0; mt < 2; ++mt)
#pragma unroll
      for (int reg = 0; reg < 4; ++reg) {
        const int r = s0 + mt * 16 + quad * 4 + reg;
        if (r < NS)
          scores[(size_t)b * NS + r] = p[mt][reg];
      }
  }
}

// ---------------- Kernel 2: exact softmax + pooling + MetaW projection ----------------
__global__ __launch_bounds__(512)
void softmax_pool(const float* __restrict__ scores,  // [B,S]
                  const float* __restrict__ mem,     // [B,S,H]
                  const float* __restrict__ MetaW,   // [4,H]
                  const float* __restrict__ Metab,   // [4]
                  float* __restrict__ out)           // [B,4]
{
  const int b    = blockIdx.x;
  const int t    = threadIdx.x;    // 0..511
  const int wave = t >> 6;         // 0..7
  const int lane = t & 63;

  __shared__ float alpha_sm[NS];
  __shared__ float red_sm[8];
  __shared__ __align__(16) float part_sm[8][NH];
  __shared__ float pooled_sm[NH];

  float sv = (t < NS) ? scores[(size_t)b * NS + t] : -INFINITY;

  float wm = sv;
#pragma unroll
  for (int off = 32; off > 0; off >>= 1)
    wm = fmaxf(wm, __shfl_xor(wm, off));
  if (lane == 0) red_sm[wave] = wm;
  __syncthreads();
  float m = red_sm[0];
#pragma unroll
  for (int w = 1; w < 8; ++w) m = fmaxf(m, red_sm[w]);

  float e = (t < NS) ? __expf(sv - m) : 0.f;
  float wsum = e;
#pragma unroll
  for (int off = 32; off > 0; off >>= 1)
    wsum += __shfl_xor(wsum, off);
  __syncthreads();
  if (lane == 0) red_sm[wave] = wsum;
  __syncthreads();
  float Z = 0.f;
#pragma unroll
  for (int w = 0; w < 8; ++w) Z += red_sm[w];
  const float Zi = 1.f / Z;

  if (t < NS) alpha_sm[t] = e * Zi;
  __syncthreads();

  f32x4 acc4 = {0.f, 0.f, 0.f, 0.f};
  const f32x4* memb = (const f32x4*)(mem + (size_t)b * NS * NH);
  for (int r = wave; r < NS; r += 8) {
    const float a = alpha_sm[r];
    const f32x4 v4 = memb[(size_t)r * (NH / 4) + lane];
    acc4[0] = fmaf(a, v4[0], acc4[0]);
    acc4[1] = fmaf(a, v4[1], acc4[1]);
    acc4[2] = fmaf(a, v4[2], acc4[2]);
    acc4[3] = fmaf(a, v4[3], acc4[3]);
  }
  *(f32x4*)&part_sm[wave][lane * 4] = acc4;
  __syncthreads();

  if (t < NH) {
    float s = 0.f;
#pragma unroll
    for (int w = 0; w < 8; ++w) s += part_sm[w][t];
    pooled_sm[t] = s;
  }
  __syncthreads();

  if (wave < 4) {
    float s = 0.f;
#pragma unroll
    for (int i = 0; i < 4; ++i) {
      const int h = i * 64 + lane;
      s = fmaf(pooled_sm[h], MetaW[(size_t)wave * NH + h], s);
    }
#pragma unroll
    for (int off = 32; off > 0; off >>= 1)
      s += __shfl_down(s, off);
    if (lane == 0)
      out[b * 4 + wave] = s + Metab[wave];
  }
}

extern "C" void kernel_launch(void* const* d_in, const int* in_sizes, int n_in,
                              void* d_out, int out_size, void* d_ws, size_t ws_size,
                              hipStream_t stream) {
  const float* mem   = (const float*)d_in[0];
  const float* lastm = (const float*)d_in[1];
  const float* U     = (const float*)d_in[2];
  const float* W     = (const float*)d_in[3];
  const float* V     = (const float*)d_in[4];
  const float* MetaW = (const float*)d_in[5];
  const float* Metab = (const float*)d_in[6];
  float* out = (float*)d_out;
  float* ws  = (float*)d_ws;

  float* scores = ws + OFF_SC;

  if (ws_size >= (size_t)WS_FLOATS_PRE * sizeof(float)) {
    float*  l_ws = ws + OFF_L;
    __bf16* Uswz = (__bf16*)(ws + OFF_UB);
    hipLaunchKernelGGL(precompute, dim3(NB + 32), dim3(256), 0, stream,
                       lastm, W, U, l_ws, Uswz);
    hipLaunchKernelGGL(scores_kernel<true>, dim3(NTASK / 4), dim3(256), 0, stream,
                       mem, lastm, U, W, V, l_ws, Uswz, scores);
  } else {
    hipLaunchKernelGGL(scores_kernel<false>, dim3(NTASK / 4), dim3(256), 0, stream,
                       mem, lastm, U, W, V, (const float*)nullptr, (const __bf16*)nullptr, scores);
  }
  hipLaunchKernelGGL(softmax_pool, dim3(NB), dim3(512), 0, stream,
                     scores, mem, MetaW, Metab, out);
}